// Round 5
// baseline (7571.931 us; speedup 1.0000x reference)
//
#include <hip/hip_runtime.h>
#include <math.h>

#define HD   256
#define RB   8      // batch rows per block
#define TB   256    // threads per block
#define TT   64     // time steps
#define NST  32     // ode steps
#define BSZ  2048

// ---------------- math helpers ----------------
__device__ __forceinline__ float sigmoidf_(float x) {
    return 1.0f / (1.0f + __expf(-x));
}
__device__ __forceinline__ float tanhf_(float x) {
    float e = __expf(2.0f * x);
    return 1.0f - 2.0f / (e + 1.0f);
}
__device__ __forceinline__ float seluf_(float x) {
    const float a = 1.6732632423543772f, s = 1.0507009873554805f;
    return x > 0.0f ? s * x : s * a * (__expf(x) - 1.0f);
}
// XLA f32 erf_inv (Giles polynomial)
__device__ __forceinline__ float erfinvf_(float x) {
    float w = -log1pf(-x * x);
    float p;
    if (w < 5.0f) {
        w -= 2.5f;
        p = 2.81022636e-08f;
        p = fmaf(p, w, 3.43273939e-07f);
        p = fmaf(p, w, -3.5233877e-06f);
        p = fmaf(p, w, -4.39150654e-06f);
        p = fmaf(p, w, 0.00021858087f);
        p = fmaf(p, w, -0.00125372503f);
        p = fmaf(p, w, -0.00417768164f);
        p = fmaf(p, w, 0.246640727f);
        p = fmaf(p, w, 1.50140941f);
    } else {
        w = sqrtf(w) - 3.0f;
        p = -0.000200214257f;
        p = fmaf(p, w, 0.000100950558f);
        p = fmaf(p, w, 0.00134934322f);
        p = fmaf(p, w, -0.00367342844f);
        p = fmaf(p, w, 0.00573950773f);
        p = fmaf(p, w, -0.0076224613f);
        p = fmaf(p, w, 0.00943887047f);
        p = fmaf(p, w, 1.00167406f);
        p = fmaf(p, w, 2.83297682f);
    }
    return p * x;
}

// ---------------- threefry2x32, key = (0, 42) ----------------
#define TF_ROUND(x0, x1, R) { x0 += x1; x1 = (x1 << (R)) | (x1 >> (32 - (R))); x1 ^= x0; }

__device__ __forceinline__ void threefry_(unsigned c0, unsigned c1, unsigned& r0, unsigned& r1) {
    const unsigned ks0 = 0u, ks1 = 42u, ks2 = 0x1BD11BDAu ^ 0u ^ 42u;
    unsigned x0 = c0 + ks0, x1 = c1 + ks1;
    TF_ROUND(x0,x1,13) TF_ROUND(x0,x1,15) TF_ROUND(x0,x1,26) TF_ROUND(x0,x1,6)
    x0 += ks1; x1 += ks2 + 1u;
    TF_ROUND(x0,x1,17) TF_ROUND(x0,x1,29) TF_ROUND(x0,x1,16) TF_ROUND(x0,x1,24)
    x0 += ks2; x1 += ks0 + 2u;
    TF_ROUND(x0,x1,13) TF_ROUND(x0,x1,15) TF_ROUND(x0,x1,26) TF_ROUND(x0,x1,6)
    x0 += ks0; x1 += ks1 + 3u;
    TF_ROUND(x0,x1,17) TF_ROUND(x0,x1,29) TF_ROUND(x0,x1,16) TF_ROUND(x0,x1,24)
    x0 += ks1; x1 += ks2 + 4u;
    TF_ROUND(x0,x1,13) TF_ROUND(x0,x1,15) TF_ROUND(x0,x1,26) TF_ROUND(x0,x1,6)
    x0 += ks2; x1 += ks0 + 5u;
    r0 = x0; r1 = x1;
}

// eps[i]: replicates jax.random.normal(key(42), (2048,256), f32) flat element i
// under jax_threefry_partitionable=True. _threefry_random_bits_partitionable:
//   counts = iota(u64) flat; (hi,lo)=(counts>>32, counts&0xffffffff)=(0, i);
//   (bits1, bits2) = threefry2x32(key, (hi, lo));
//   for bit_width < 64: bits = convert(bits1 ^ bits2)   <-- XOR, not truncation.
// [V4; V1 (original path), V2 (o1), V3 (o0) eliminated empirically]
__device__ __forceinline__ float jax_normal_(unsigned i) {
    unsigned o0, o1;
    threefry_(0u, i, o0, o1);
    unsigned bits = o0 ^ o1;
    unsigned fb = (bits >> 9) | 0x3F800000u;
    float f = __uint_as_float(fb) - 1.0f;           // [0,1)
    const float lo = -0.99999994f;                  // nextafter(-1,0)
    float u = f * 2.0f + lo;                        // (maxval-minval) rounds to 2.0f
    u = fmaxf(lo, u);
    return 1.41421356237f * erfinvf_(u);
}

// ---------------- block-level 256->256 dense layer, direct row reads ----------------
// in [RB][HD] (LDS), out [RB][HD] (LDS), W [256 out][256 k] row-major (global, L1/L2-hot)
// thread tid owns output o = tid for all RB rows. ACT: 0 none, 1 selu, 2 relu
template<int ACT>
__device__ __forceinline__ void layerD(const float (*in)[HD], float (*out)[HD],
                                       const float* __restrict__ W,
                                       const float* __restrict__ b, int tid) {
    const int o = tid;
    float acc[RB];
    const float bb = b[o];
#pragma unroll
    for (int r = 0; r < RB; ++r) acc[r] = bb;
    const float* wrow = W + (size_t)o * HD;
#pragma unroll 4
    for (int k0 = 0; k0 < HD; k0 += 4) {
        const float4 w = *(const float4*)(wrow + k0);
#pragma unroll
        for (int r = 0; r < RB; ++r) {
            const float4 iv = *(const float4*)(&in[r][k0]);
            acc[r] = fmaf(iv.w, w.w, fmaf(iv.z, w.z, fmaf(iv.y, w.y, fmaf(iv.x, w.x, acc[r]))));
        }
    }
#pragma unroll
    for (int r = 0; r < RB; ++r) {
        float v = acc[r];
        if (ACT == 1) v = seluf_(v);
        if (ACT == 2) v = fmaxf(v, 0.0f);
        out[r][o] = v;
    }
}

__device__ __forceinline__ void ode_f2(const float (*y)[HD], float (*kout)[HD],
                                       float (*tA)[HD], float (*tB)[HD],
                                       const float* oW1, const float* oW2,
                                       const float* oW3, const float* oW4,
                                       const float* b1, const float* b2,
                                       const float* b3, const float* b4, int tid) {
    layerD<1>(y,  tA,   oW1, b1, tid); __syncthreads();
    layerD<1>(tA, tB,   oW2, b2, tid); __syncthreads();
    layerD<1>(tB, tA,   oW3, b3, tid); __syncthreads();
    layerD<0>(tA, kout, oW4, b4, tid); __syncthreads();
}

// ---------------- fused pipeline kernel (no workspace, direct weight reads) ----------------
__global__ __launch_bounds__(TB) void fused_kernel(
    const float* __restrict__ x,      // [2048][64][4]
    const float* __restrict__ meta,   // [2048][4]
    const float* __restrict__ W_ih,   // [768][8]
    const float* __restrict__ W_hh,   // [768][256]
    const float* __restrict__ b_ih,   // [768]
    const float* __restrict__ b_hh,   // [768]
    const float* __restrict__ eW1,    // [256][256]
    const float* __restrict__ eb1,    // [256]
    const float* __restrict__ eW2,    // [512][256]
    const float* __restrict__ eb2,    // [512]
    const float* __restrict__ oW1, const float* __restrict__ ob1,
    const float* __restrict__ oW2, const float* __restrict__ ob2,
    const float* __restrict__ oW3, const float* __restrict__ ob3,
    const float* __restrict__ oW4, const float* __restrict__ ob4,
    const float* __restrict__ outW,   // [260]
    const float* __restrict__ outb,   // [1]
    float* __restrict__ out)          // [2048]
{
    const int tid = threadIdx.x;
    const int j = tid;
    const int b0 = blockIdx.x * RB;

    __shared__ float xall[RB][TT * 4];   // 8 KB
    __shared__ float meta_s[RB][4];
    __shared__ float h_s[RB][HD];        // h, later y
    __shared__ float tA[RB][HD];
    __shared__ float tB[RB][HD];
    __shared__ float ytmp[RB][HD];
    __shared__ float kb[6][RB][HD];      // k1..k6
    __shared__ float dt_s[RB];
    __shared__ float red[TB];

    // ---- stage x, meta; zero h ----
#pragma unroll
    for (int i = 0; i < RB; ++i) {
        int idx = tid + i * TB;          // 0..2047
        int r = idx >> 8, c = idx & 255;
        xall[r][c] = x[(size_t)(b0 + r) * 256 + c];
    }
    if (tid < 32) { int r = tid >> 2, m = tid & 3; meta_s[r][m] = meta[(b0 + r) * 4 + m]; }
#pragma unroll
    for (int r = 0; r < RB; ++r) h_s[r][j] = 0.0f;
    __syncthreads();

    // ---- GRU: thread j owns hidden index j; gate rows j (r), j+256 (z), j+512 (n) ----
    float wir[8], wiz[8], win[8];
#pragma unroll
    for (int d = 0; d < 8; ++d) {
        wir[d] = W_ih[(size_t)j * 8 + d];
        wiz[d] = W_ih[(size_t)(j + 256) * 8 + d];
        win[d] = W_ih[(size_t)(j + 512) * 8 + d];
    }
    const float* wr_row = W_hh + (size_t)j * HD;
    const float* wz_row = W_hh + (size_t)(j + 256) * HD;
    const float* wn_row = W_hh + (size_t)(j + 512) * HD;

    float base_r[RB], base_z[RB], base_xn[RB];
    {
        const float bir = b_ih[j], biz = b_ih[j + 256], bin_ = b_ih[j + 512];
        const float bhr = b_hh[j], bhz = b_hh[j + 256];
#pragma unroll
        for (int r = 0; r < RB; ++r) {
            float sr = bir + bhr, sz = biz + bhz, sn = bin_;
#pragma unroll
            for (int m = 0; m < 4; ++m) {
                float mv = meta_s[r][m];
                sr = fmaf(mv, wir[4 + m], sr);
                sz = fmaf(mv, wiz[4 + m], sz);
                sn = fmaf(mv, win[4 + m], sn);
            }
            base_r[r] = sr; base_z[r] = sz; base_xn[r] = sn;
        }
    }
    const float bhn = b_hh[j + 512];

    for (int t = 0; t < TT; ++t) {
        float ar[RB], az[RB], axn[RB], ahn[RB];
#pragma unroll
        for (int r = 0; r < RB; ++r) { ar[r] = base_r[r]; az[r] = base_z[r]; axn[r] = base_xn[r]; ahn[r] = bhn; }
#pragma unroll
        for (int k = 0; k < 4; ++k) {
#pragma unroll
            for (int r = 0; r < RB; ++r) {
                float xv = xall[r][t * 4 + k];
                ar[r]  = fmaf(xv, wir[k], ar[r]);
                az[r]  = fmaf(xv, wiz[k], az[r]);
                axn[r] = fmaf(xv, win[k], axn[r]);
            }
        }
#pragma unroll 4
        for (int k0 = 0; k0 < HD; k0 += 4) {
            const float4 wr4 = *(const float4*)(wr_row + k0);
            const float4 wz4 = *(const float4*)(wz_row + k0);
            const float4 wn4 = *(const float4*)(wn_row + k0);
#pragma unroll
            for (int r = 0; r < RB; ++r) {
                const float4 hv = *(const float4*)(&h_s[r][k0]);
                ar[r]  = fmaf(hv.w, wr4.w, fmaf(hv.z, wr4.z, fmaf(hv.y, wr4.y, fmaf(hv.x, wr4.x, ar[r]))));
                az[r]  = fmaf(hv.w, wz4.w, fmaf(hv.z, wz4.z, fmaf(hv.y, wz4.y, fmaf(hv.x, wz4.x, az[r]))));
                ahn[r] = fmaf(hv.w, wn4.w, fmaf(hv.z, wn4.z, fmaf(hv.y, wn4.y, fmaf(hv.x, wn4.x, ahn[r]))));
            }
        }
        __syncthreads();
#pragma unroll
        for (int r = 0; r < RB; ++r) {
            float rg = sigmoidf_(ar[r]);
            float zg = sigmoidf_(az[r]);
            float ng = tanhf_(fmaf(rg, ahn[r], axn[r]));
            float hp = h_s[r][j];
            h_s[r][j] = fmaf(zg, hp - ng, ng);   // (1-z)*n + z*h
        }
        __syncthreads();
    }

    // ---- encoder: h1 = relu(h@eW1.T+eb1) -> tA ; mean/std rows j / j+256 of eW2 ----
    layerD<2>(h_s, tA, eW1, eb1, tid);
    __syncthreads();
    {
        float am[RB], as_[RB];
        const float bm = eb2[j], bs = eb2[j + 256];
#pragma unroll
        for (int r = 0; r < RB; ++r) { am[r] = bm; as_[r] = bs; }
        const float* wmrow = eW2 + (size_t)j * HD;
        const float* wsrow = eW2 + (size_t)(j + 256) * HD;
#pragma unroll 4
        for (int k0 = 0; k0 < HD; k0 += 4) {
            const float4 wm = *(const float4*)(wmrow + k0);
            const float4 ws4 = *(const float4*)(wsrow + k0);
#pragma unroll
            for (int r = 0; r < RB; ++r) {
                const float4 hv = *(const float4*)(&tA[r][k0]);
                am[r]  = fmaf(hv.w, wm.w, fmaf(hv.z, wm.z, fmaf(hv.y, wm.y, fmaf(hv.x, wm.x, am[r]))));
                as_[r] = fmaf(hv.w, ws4.w, fmaf(hv.z, ws4.z, fmaf(hv.y, ws4.y, fmaf(hv.x, ws4.x, as_[r]))));
            }
        }
#pragma unroll
        for (int r = 0; r < RB; ++r) {
            unsigned i = (unsigned)((b0 + r) * HD + j);
            float e = jax_normal_(i);
            h_s[r][j] = fmaf(e, as_[r], am[r]);   // y0 = eps*std + mean
        }
    }
    if (tid < RB) dt_s[tid] = (xall[tid][252] - xall[tid][0]) * (1.0f / 32.0f);
    __syncthreads();

    // ---- dopri5, 32 steps ----
    const float A21 = (float)(1.0/5.0);
    const float A31 = (float)(3.0/40.0),      A32 = (float)(9.0/40.0);
    const float A41 = (float)(44.0/45.0),     A42 = (float)(-56.0/15.0),    A43 = (float)(32.0/9.0);
    const float A51 = (float)(19372.0/6561.0),A52 = (float)(-25360.0/2187.0),
                A53 = (float)(64448.0/6561.0),A54 = (float)(-212.0/729.0);
    const float A61 = (float)(9017.0/3168.0), A62 = (float)(-355.0/33.0),
                A63 = (float)(46732.0/5247.0),A64 = (float)(49.0/176.0),    A65 = (float)(-5103.0/18656.0);
    const float B1f = (float)(35.0/384.0),    B3f = (float)(500.0/1113.0),  B4f = (float)(125.0/192.0),
                B5f = (float)(-2187.0/6784.0),B6f = (float)(11.0/84.0);

    for (int st = 0; st < NST; ++st) {
        ode_f2(h_s, kb[0], tA, tB, oW1, oW2, oW3, oW4, ob1, ob2, ob3, ob4, tid);
#pragma unroll
        for (int r = 0; r < RB; ++r)
            ytmp[r][j] = fmaf(dt_s[r], A21 * kb[0][r][j], h_s[r][j]);
        __syncthreads();

        ode_f2(ytmp, kb[1], tA, tB, oW1, oW2, oW3, oW4, ob1, ob2, ob3, ob4, tid);
#pragma unroll
        for (int r = 0; r < RB; ++r) {
            float s = fmaf(A32, kb[1][r][j], A31 * kb[0][r][j]);
            ytmp[r][j] = fmaf(dt_s[r], s, h_s[r][j]);
        }
        __syncthreads();

        ode_f2(ytmp, kb[2], tA, tB, oW1, oW2, oW3, oW4, ob1, ob2, ob3, ob4, tid);
#pragma unroll
        for (int r = 0; r < RB; ++r) {
            float s = fmaf(A43, kb[2][r][j], fmaf(A42, kb[1][r][j], A41 * kb[0][r][j]));
            ytmp[r][j] = fmaf(dt_s[r], s, h_s[r][j]);
        }
        __syncthreads();

        ode_f2(ytmp, kb[3], tA, tB, oW1, oW2, oW3, oW4, ob1, ob2, ob3, ob4, tid);
#pragma unroll
        for (int r = 0; r < RB; ++r) {
            float s = fmaf(A54, kb[3][r][j], fmaf(A53, kb[2][r][j], fmaf(A52, kb[1][r][j], A51 * kb[0][r][j])));
            ytmp[r][j] = fmaf(dt_s[r], s, h_s[r][j]);
        }
        __syncthreads();

        ode_f2(ytmp, kb[4], tA, tB, oW1, oW2, oW3, oW4, ob1, ob2, ob3, ob4, tid);
#pragma unroll
        for (int r = 0; r < RB; ++r) {
            float s = fmaf(A65, kb[4][r][j], fmaf(A64, kb[3][r][j],
                      fmaf(A63, kb[2][r][j], fmaf(A62, kb[1][r][j], A61 * kb[0][r][j]))));
            ytmp[r][j] = fmaf(dt_s[r], s, h_s[r][j]);
        }
        __syncthreads();

        ode_f2(ytmp, kb[5], tA, tB, oW1, oW2, oW3, oW4, ob1, ob2, ob3, ob4, tid);
#pragma unroll
        for (int r = 0; r < RB; ++r) {
            float s = fmaf(B6f, kb[5][r][j], fmaf(B5f, kb[4][r][j],
                      fmaf(B4f, kb[3][r][j], fmaf(B3f, kb[2][r][j], B1f * kb[0][r][j]))));
            h_s[r][j] = fmaf(dt_s[r], s, h_s[r][j]);
        }
        __syncthreads();
    }

    // ---- output head ----
    const float wj = outW[j];
    for (int r = 0; r < RB; ++r) {
        red[tid] = h_s[r][j] * wj;
        __syncthreads();
        for (int s = 128; s > 0; s >>= 1) {
            if (tid < s) red[tid] += red[tid + s];
            __syncthreads();
        }
        if (tid == 0) {
            float acc = red[0] + outb[0];
#pragma unroll
            for (int m = 0; m < 4; ++m) acc = fmaf(meta_s[r][m], outW[HD + m], acc);
            out[b0 + r] = acc;
        }
        __syncthreads();
    }
}

extern "C" void kernel_launch(void* const* d_in, const int* in_sizes, int n_in,
                              void* d_out, int out_size, void* d_ws, size_t ws_size,
                              hipStream_t stream) {
    const float* x    = (const float*)d_in[0];
    const float* meta = (const float*)d_in[1];
    const float* W_ih = (const float*)d_in[2];
    const float* W_hh = (const float*)d_in[3];
    const float* b_ih = (const float*)d_in[4];
    const float* b_hh = (const float*)d_in[5];
    const float* eW1  = (const float*)d_in[6];
    const float* eb1  = (const float*)d_in[7];
    const float* eW2  = (const float*)d_in[8];
    const float* eb2  = (const float*)d_in[9];
    const float* oW1  = (const float*)d_in[10];
    const float* ob1  = (const float*)d_in[11];
    const float* oW2  = (const float*)d_in[12];
    const float* ob2  = (const float*)d_in[13];
    const float* oW3  = (const float*)d_in[14];
    const float* ob3  = (const float*)d_in[15];
    const float* oW4  = (const float*)d_in[16];
    const float* ob4  = (const float*)d_in[17];
    const float* outW = (const float*)d_in[18];
    const float* outb = (const float*)d_in[19];

    fused_kernel<<<BSZ / RB, TB, 0, stream>>>(x, meta, W_ih, W_hh, b_ih, b_hh,
                                              eW1, eb1, eW2, eb2,
                                              oW1, ob1, oW2, ob2, oW3, ob3, oW4, ob4,
                                              outW, outb, (float*)d_out);
}